// Round 3
// baseline (492.138 us; speedup 1.0000x reference)
//
#include <hip/hip_runtime.h>

typedef unsigned short ushort_t;
typedef __bf16 bf16x8 __attribute__((ext_vector_type(8)));
typedef __bf16 bf16x2 __attribute__((ext_vector_type(2)));
typedef float f32x4 __attribute__((ext_vector_type(4)));

#define LOG2E 1.4426950408889634f
#define LN2   0.6931471805599453f

__device__ __forceinline__ ushort_t f2bf(float f) {
    unsigned u;
    __builtin_memcpy(&u, &f, 4);
    u += 0x7fffu + ((u >> 16) & 1u);   // RNE
    return (ushort_t)(u >> 16);
}

// inputs pre-scaled by log2(e): silu2(y) = y * sigmoid2(y) = log2e*silu(x).
// Downstream weights carry the compensating ln2.
//
// Quad-batched form: ONE v_rcp serves four sigmoids (trans pipe is the
// suspected saturated resource; rcp count drops 4x at +13 cheap VALU ops).
// clamp y >= -30 so d = 1+exp2(-y) <= 2^30 and the 4-term product stays
// finite (error from clamp < 3e-8, far below tolerance).
__device__ __forceinline__ void silu2x4(float y0, float y1, float y2, float y3,
                                        float& o0, float& o1, float& o2, float& o3) {
    float e0 = __builtin_amdgcn_exp2f(-fmaxf(y0, -30.0f));
    float e1 = __builtin_amdgcn_exp2f(-fmaxf(y1, -30.0f));
    float e2 = __builtin_amdgcn_exp2f(-fmaxf(y2, -30.0f));
    float e3 = __builtin_amdgcn_exp2f(-fmaxf(y3, -30.0f));
    float d0 = 1.0f + e0, d1 = 1.0f + e1, d2 = 1.0f + e2, d3 = 1.0f + e3;
    float p01 = d0 * d1, p23 = d2 * d3;
    float r   = __builtin_amdgcn_rcpf(p01 * p23);
    float r01 = p23 * r, r23 = p01 * r;     // = 1/(d0*d1), 1/(d2*d3)
    o0 = y0 * (d1 * r01);
    o1 = y1 * (d0 * r01);
    o2 = y2 * (d3 * r23);
    o3 = y3 * (d2 * r23);
}

__device__ __forceinline__ float rdlane(float v, int l) {
    return __builtin_bit_cast(float, __builtin_amdgcn_readlane(__builtin_bit_cast(int, v), l));
}

// XOR-swizzled A-fragment LDS layout for 16x16x32 bf16 MFMA (verified R3):
// element (row,k) -> frag  = (k>>5)   [within a wave's 16-row region]
//                    slot  = ((row&15) ^ ((k>>5)&3) ^ (((k>>3)&3)<<2))
//                            + 16*((k>>3)&3)                             [16 B]
//                    byte  = (k&7)*2
// Reads: b128, 64 distinct slots, conflict-free. Writes: 2-way (free).
//
// 512-thread blocks (8 waves): sW1 32 KB staged ONCE per block and shared
// by 8 waves; sH0 4 KB/wave * 8 = 32 KB. LDS = 64 KB -> 2 blocks/CU ->
// 16 waves/CU (was 12). Hot loop stays barrier-free: each wave owns frags
// [4w, 4w+4) of sH0 exclusively; wave-local DS ops are in-order.

// Packed scatter accumulator: one f64 atomic carries sum + 65536*count.
#define CNT_UNIT 65536.0

__global__ __launch_bounds__(512, 4) void mlp_kernel(
    const float* __restrict__ v,    // [N,3] f32
    const float* __restrict__ rij,  // [E,3] f32
    const float* __restrict__ W0,   // [128,4]
    const float* __restrict__ b0,   // [128]
    const float* __restrict__ W1,   // [128,128] (n,k)
    const float* __restrict__ b1,   // [128]
    const float* __restrict__ W2,   // [128]
    const float* __restrict__ b2,   // [1]
    const int* __restrict__ eidx,   // [2,E] int32
    double* __restrict__ acc_i, double* __restrict__ acc_j,
    int E, int nchunks)             // chunk = 128 edges (8 waves x 16)
{
    __shared__ ushort_t sW1[16384];   // 32 KB, frag layout (unswizzled)
    __shared__ ushort_t sH0[16384];   // 32 KB, XOR-swizzled; wave w owns frags [4w,4w+4)

    const int tid  = threadIdx.x;
    const int lane = tid & 63;
    const int wave = tid >> 6;

    // ---- stage W1 (f32 -> bf16) into LDS (once per block) ----
    // W1's silu-prescale (log2e) cancels against h0' (ln2): staged UNSCALED.
    {
        int n = tid >> 2, qr = tid & 3;
        const float* src = W1 + n * 128;
#pragma unroll
        for (int dk = 0; dk < 4; dk++) {
            int k0   = qr * 32 + dk * 8;
            int frag = (n >> 4) * 4 + (k0 >> 5);
            int slot = (n & 15) + 16 * ((k0 >> 3) & 3);
            ushort_t tmp[8];
#pragma unroll
            for (int t = 0; t < 8; t++) tmp[t] = f2bf(src[k0 + t]);
            *(uint4*)(&sW1[frag * 512 + slot * 8]) = *(const uint4*)tmp;
        }
    }

    // ---- per-lane constants (log2e/ln2 folded) ----
    float4 w0q[2]; float b0v[2];
#pragma unroll
    for (int kk = 0; kk < 2; kk++) {
        int h = 2 * lane + kk;
        w0q[kk].x = W0[h * 4 + 0] * LOG2E;
        w0q[kk].y = W0[h * 4 + 1] * LOG2E;
        w0q[kk].z = W0[h * 4 + 2] * LOG2E;
        w0q[kk].w = W0[h * 4 + 3] * LOG2E;
        b0v[kk]   = b0[h] * LOG2E;
    }
    float b1v[8], w2v[8];
#pragma unroll
    for (int nt = 0; nt < 8; nt++) {
        int ccol = nt * 16 + (lane & 15);
        b1v[nt] = b1[ccol] * LOG2E;   // pre-activation scale for layer-1 silu
        w2v[nt] = W2[ccol] * LN2;     // compensates the log2e in silu2 output
    }
    const float b2f = b2[0];

    __syncthreads();   // sW1 ready; hot loop below is barrier-free

    const int q = lane >> 4, c = lane & 15, p = (lane >> 2) & 3, bsub = lane & 3;
    const int ple  = lane >> 2;     // edge-in-wave this lane preloads
    const int comp = lane & 3;      // 0..2: v component, 3: |r|/H

    // ---- gather preload for one chunk (lane-parallel) ----
    auto preload = [&](int ch, float& val_o, int& idx_o) {
        float val = 0.f; int idxr = 0;
        int pe = ch * 128 + wave * 16 + ple;
        if (ch < nchunks && pe < E) {
            if (comp == 3) {
                float r0 = rij[3 * pe], r1 = rij[3 * pe + 1], r2 = rij[3 * pe + 2];
                val = sqrtf(fmaf(r0, r0, fmaf(r1, r1, r2 * r2))) * (1.0f / 3.0f);
            } else {
                int i = eidx[pe], jj = eidx[E + pe];
                idxr = (comp == 1) ? jj : i;
                val = v[3 * i + comp] - v[3 * jj + comp];
            }
        }
        val_o = val; idx_o = idxr;
    };

    float val; int idxr;
    preload(blockIdx.x, val, idxr);   // prologue load for first chunk

    for (int chunk = blockIdx.x; chunk < nchunks; chunk += gridDim.x) {
        const float val_cur = val;
        const int   idx_cur = idxr;
        // issue next chunk's gathers now; consumed one full iteration later
        preload(chunk + (int)gridDim.x, val, idxr);

        const int ebase = chunk * 128 + wave * 16;

        // ===== two temporal halves: layer0 -> 16-row LDS region -> A-frags =====
        bf16x8 afr[2][4];
#pragma unroll
        for (int half = 0; half < 2; ++half) {
#pragma unroll
            for (int le = 0; le < 8; le++) {
                int se = half * 8 + le;
                float vx = rdlane(val_cur, se * 4 + 0);
                float vy = rdlane(val_cur, se * 4 + 1);
                float vz = rdlane(val_cur, se * 4 + 2);
                float rr = rdlane(val_cur, se * 4 + 3);
                float cc0 = fmaf(w0q[0].x, rr, b0v[0]);
                float dd0 = fmaf(w0q[0].y, vx, fmaf(w0q[0].z, vy, w0q[0].w * vz));
                float cc1 = fmaf(w0q[1].x, rr, b0v[1]);
                float dd1 = fmaf(w0q[1].y, vx, fmaf(w0q[1].z, vy, w0q[1].w * vz));
                float s0, s1, s2, s3;
                silu2x4(cc0 + dd0, cc0 - dd0, cc1 + dd1, cc1 - dd1, s0, s1, s2, s3);
                bf16x2 pki, pkj;
                pki[0] = (__bf16)s0; pki[1] = (__bf16)s2;   // x_i: h=2l, 2l+1
                pkj[0] = (__bf16)s1; pkj[1] = (__bf16)s3;   // x_j
                int mi = 2 * le;                  // x_i row in [0,16); x_j row = mi+1
                int fr = wave * 4 + q;
                int sli = ((mi ^ q ^ (p << 2)) & 15) + (p << 4);
                int slj = (((mi + 1) ^ q ^ (p << 2)) & 15) + (p << 4);
                ((unsigned*)sH0)[fr * 256 + sli * 4 + bsub] = __builtin_bit_cast(unsigned, pki);
                ((unsigned*)sH0)[fr * 256 + slj * 4 + bsub] = __builtin_bit_cast(unsigned, pkj);
            }
            // cache this half's A-fragments before half 1 overwrites the region
#pragma unroll
            for (int ks = 0; ks < 4; ks++) {
                int sl_rd = (((lane & 15) ^ ks ^ (q << 2)) & 15) + 16 * q;
                afr[half][ks] = *(const bf16x8*)(&sH0[(wave * 4 + ks) * 512 + sl_rd * 8]);
            }
        }

        // ===== GEMM: h1_pre' = H0' @ W1^T + b1' (B read once, feeds both halves) =====
        f32x4 acc[2][8];
#pragma unroll
        for (int t = 0; t < 2; t++)
#pragma unroll
            for (int nt = 0; nt < 8; nt++)
                acc[t][nt] = (f32x4){b1v[nt], b1v[nt], b1v[nt], b1v[nt]};

#pragma unroll
        for (int ks = 0; ks < 4; ks++) {
#pragma unroll
            for (int nt = 0; nt < 8; nt++) {
                bf16x8 bb = *(const bf16x8*)(&sW1[(nt * 4 + ks) * 512 + lane * 8]);
                acc[0][nt] = __builtin_amdgcn_mfma_f32_16x16x32_bf16(afr[0][ks], bb, acc[0][nt], 0, 0, 0);
                acc[1][nt] = __builtin_amdgcn_mfma_f32_16x16x32_bf16(afr[1][ks], bb, acc[1][nt], 0, 0, 0);
            }
        }

        // ===== epilogue: silu2(h1') . (W2*ln2) -> +b2 -> packed f64 scatter-add =====
        float rs[2][4] = {{0.f, 0.f, 0.f, 0.f}, {0.f, 0.f, 0.f, 0.f}};
#pragma unroll
        for (int t = 0; t < 2; t++)
#pragma unroll
            for (int nt = 0; nt < 8; nt++) {
                float s0, s1, s2, s3;
                silu2x4(acc[t][nt][0], acc[t][nt][1], acc[t][nt][2], acc[t][nt][3],
                        s0, s1, s2, s3);
                rs[t][0] = fmaf(s0, w2v[nt], rs[t][0]);
                rs[t][1] = fmaf(s1, w2v[nt], rs[t][1]);
                rs[t][2] = fmaf(s2, w2v[nt], rs[t][2]);
                rs[t][3] = fmaf(s3, w2v[nt], rs[t][3]);
            }
#pragma unroll
        for (int t = 0; t < 2; t++)
#pragma unroll
            for (int r = 0; r < 4; r++) {
                float s = rs[t][r];
                s += __shfl_xor(s, 1, 64);
                s += __shfl_xor(s, 2, 64);
                s += __shfl_xor(s, 4, 64);
                s += __shfl_xor(s, 8, 64);
                int el  = t * 8 + q * 2 + (r >> 1);        // edge within wave's 16
                int src = el * 4 + (r & 1);                // comp0 lane holds i, comp1 holds j
                int node = __shfl(idx_cur, src, 64);
                int e = ebase + el;
                if (c == 0 && e < E) {
                    double contrib = (double)(s + b2f) + CNT_UNIT;
                    if (r & 1) atomicAdd(&acc_j[node], contrib);
                    else       atomicAdd(&acc_i[node], contrib);
                }
            }
        // wave-local LDS WAR across chunks is safe: one wave's DS ops are in-order.
    }
}

__global__ void finalize_kernel(const double* __restrict__ acc_i,
                                const double* __restrict__ acc_j,
                                float* __restrict__ out, int N)
{
    int n = blockIdx.x * 256 + threadIdx.x;
    if (n < N) {
        double ti = acc_i[n], tj = acc_j[n];
        double ci = rint(ti * (1.0 / CNT_UNIT));
        double cj = rint(tj * (1.0 / CNT_UNIT));
        double si = ti - ci * CNT_UNIT;
        double sj = tj - cj * CNT_UNIT;
        out[n] = (float)(si / fmax(ci, 1.0) + sj / fmax(cj, 1.0));
    }
}

extern "C" void kernel_launch(void* const* d_in, const int* in_sizes, int n_in,
                              void* d_out, int out_size, void* d_ws, size_t ws_size,
                              hipStream_t stream) {
    const float* v   = (const float*)d_in[0];
    const float* rij = (const float*)d_in[1];
    const float* W0  = (const float*)d_in[2];
    const float* b0  = (const float*)d_in[3];
    const float* W1  = (const float*)d_in[4];
    const float* b1  = (const float*)d_in[5];
    const float* W2  = (const float*)d_in[6];
    const float* b2  = (const float*)d_in[7];
    const int* eidx  = (const int*)d_in[8];

    const int E = in_sizes[1] / 3;
    const int N = out_size;

    double* acc_i = (double*)d_ws;
    double* acc_j = acc_i + N;

    hipMemsetAsync(d_ws, 0, (size_t)2 * N * sizeof(double), stream);

    int nchunks = (E + 127) / 128;      // 128 edges per block-chunk (8 waves)
    int grid = nchunks < 512 ? nchunks : 512;
    mlp_kernel<<<grid, 512, 0, stream>>>(v, rij, W0, b0, W1, b1, W2, b2, eidx,
                                         acc_i, acc_j, E, nchunks);
    finalize_kernel<<<(N + 255) / 256, 256, 0, stream>>>(acc_i, acc_j,
                                                         (float*)d_out, N);
}

// Round 4
// 427.863 us; speedup vs baseline: 1.1502x; 1.1502x over previous
//
#include <hip/hip_runtime.h>

typedef unsigned short ushort_t;
typedef __bf16 bf16x8 __attribute__((ext_vector_type(8)));
typedef __bf16 bf16x2 __attribute__((ext_vector_type(2)));
typedef float f32x4 __attribute__((ext_vector_type(4)));

#define LOG2E 1.4426950408889634f
#define LN2   0.6931471805599453f

__device__ __forceinline__ ushort_t f2bf(float f) {
    unsigned u;
    __builtin_memcpy(&u, &f, 4);
    u += 0x7fffu + ((u >> 16) & 1u);   // RNE
    return (ushort_t)(u >> 16);
}

// inputs pre-scaled by log2(e): silu2(y) = y * sigmoid2(y) = log2e*silu(x).
// Downstream weights carry the compensating ln2.
//
// Quad-batched form: ONE v_rcp serves four sigmoids (trans-pipe relief;
// validated in R3: absmax unchanged). clamp y >= -30 keeps the 4-term
// product finite (error < 3e-8).
__device__ __forceinline__ void silu2x4(float y0, float y1, float y2, float y3,
                                        float& o0, float& o1, float& o2, float& o3) {
    float e0 = __builtin_amdgcn_exp2f(-fmaxf(y0, -30.0f));
    float e1 = __builtin_amdgcn_exp2f(-fmaxf(y1, -30.0f));
    float e2 = __builtin_amdgcn_exp2f(-fmaxf(y2, -30.0f));
    float e3 = __builtin_amdgcn_exp2f(-fmaxf(y3, -30.0f));
    float d0 = 1.0f + e0, d1 = 1.0f + e1, d2 = 1.0f + e2, d3 = 1.0f + e3;
    float p01 = d0 * d1, p23 = d2 * d3;
    float r   = __builtin_amdgcn_rcpf(p01 * p23);
    float r01 = p23 * r, r23 = p01 * r;     // = 1/(d0*d1), 1/(d2*d3)
    o0 = y0 * (d1 * r01);
    o1 = y1 * (d0 * r01);
    o2 = y2 * (d3 * r23);
    o3 = y3 * (d2 * r23);
}

__device__ __forceinline__ float rdlane(float v, int l) {
    return __builtin_bit_cast(float, __builtin_amdgcn_readlane(__builtin_bit_cast(int, v), l));
}

// XOR-swizzled A-fragment LDS layout for 16x16x32 bf16 MFMA (verified R3):
// element (row,k) -> frag  = (k>>5)   [within a wave's 16-row region]
//                    slot  = ((row&15) ^ ((k>>5)&3) ^ (((k>>3)&3)<<2))
//                            + 16*((k>>3)&3)                             [16 B]
//                    byte  = (k&7)*2
// Reads: b128, 64 distinct slots, conflict-free. Writes: 2-way (free).
//
// 512-thread blocks (8 waves): sW1 32 KB staged ONCE per block and shared
// by 8 waves; sH0 4 KB/wave * 8 = 32 KB. LDS = 64 KB -> 2 blocks/CU ->
// 16 waves/CU. Hot loop stays barrier-free: each wave owns frags
// [4w, 4w+4) of sH0 exclusively; wave-local DS ops are in-order.
//
// __launch_bounds__(512, 2): HIP's 2nd arg acts as min BLOCKS/CU (R3
// post-mortem: (512,4) forced 8 waves/SIMD -> 64-VGPR cap -> 1 GB of
// scratch-spill traffic, +34% dur). 2 blocks/CU matches the LDS limit and
// caps VGPR at 128 >= the ~84-100 this code needs. DO NOT RAISE.

// Packed scatter accumulator: one f64 atomic carries sum + 65536*count.
#define CNT_UNIT 65536.0

__global__ __launch_bounds__(512, 2) void mlp_kernel(
    const float* __restrict__ v,    // [N,3] f32
    const float* __restrict__ rij,  // [E,3] f32
    const float* __restrict__ W0,   // [128,4]
    const float* __restrict__ b0,   // [128]
    const float* __restrict__ W1,   // [128,128] (n,k)
    const float* __restrict__ b1,   // [128]
    const float* __restrict__ W2,   // [128]
    const float* __restrict__ b2,   // [1]
    const int* __restrict__ eidx,   // [2,E] int32
    double* __restrict__ acc_i, double* __restrict__ acc_j,
    int E, int nchunks)             // chunk = 128 edges (8 waves x 16)
{
    __shared__ ushort_t sW1[16384];   // 32 KB, frag layout (unswizzled)
    __shared__ ushort_t sH0[16384];   // 32 KB, XOR-swizzled; wave w owns frags [4w,4w+4)

    const int tid  = threadIdx.x;
    const int lane = tid & 63;
    const int wave = tid >> 6;

    // ---- stage W1 (f32 -> bf16) into LDS (once per block) ----
    // W1's silu-prescale (log2e) cancels against h0' (ln2): staged UNSCALED.
    {
        int n = tid >> 2, qr = tid & 3;
        const float* src = W1 + n * 128;
#pragma unroll
        for (int dk = 0; dk < 4; dk++) {
            int k0   = qr * 32 + dk * 8;
            int frag = (n >> 4) * 4 + (k0 >> 5);
            int slot = (n & 15) + 16 * ((k0 >> 3) & 3);
            ushort_t tmp[8];
#pragma unroll
            for (int t = 0; t < 8; t++) tmp[t] = f2bf(src[k0 + t]);
            *(uint4*)(&sW1[frag * 512 + slot * 8]) = *(const uint4*)tmp;
        }
    }

    // ---- per-lane constants (log2e/ln2 folded) ----
    float4 w0q[2]; float b0v[2];
#pragma unroll
    for (int kk = 0; kk < 2; kk++) {
        int h = 2 * lane + kk;
        w0q[kk].x = W0[h * 4 + 0] * LOG2E;
        w0q[kk].y = W0[h * 4 + 1] * LOG2E;
        w0q[kk].z = W0[h * 4 + 2] * LOG2E;
        w0q[kk].w = W0[h * 4 + 3] * LOG2E;
        b0v[kk]   = b0[h] * LOG2E;
    }
    float b1v[8], w2v[8];
#pragma unroll
    for (int nt = 0; nt < 8; nt++) {
        int ccol = nt * 16 + (lane & 15);
        b1v[nt] = b1[ccol] * LOG2E;   // pre-activation scale for layer-1 silu
        w2v[nt] = W2[ccol] * LN2;     // compensates the log2e in silu2 output
    }
    const float b2f = b2[0];

    __syncthreads();   // sW1 ready; hot loop below is barrier-free

    const int q = lane >> 4, c = lane & 15, p = (lane >> 2) & 3, bsub = lane & 3;
    const int ple  = lane >> 2;     // edge-in-wave this lane preloads
    const int comp = lane & 3;      // 0..2: v component, 3: |r|/H

    // ---- gather preload for one chunk (lane-parallel) ----
    auto preload = [&](int ch, float& val_o, int& idx_o) {
        float val = 0.f; int idxr = 0;
        int pe = ch * 128 + wave * 16 + ple;
        if (ch < nchunks && pe < E) {
            if (comp == 3) {
                float r0 = rij[3 * pe], r1 = rij[3 * pe + 1], r2 = rij[3 * pe + 2];
                val = sqrtf(fmaf(r0, r0, fmaf(r1, r1, r2 * r2))) * (1.0f / 3.0f);
            } else {
                int i = eidx[pe], jj = eidx[E + pe];
                idxr = (comp == 1) ? jj : i;
                val = v[3 * i + comp] - v[3 * jj + comp];
            }
        }
        val_o = val; idx_o = idxr;
    };

    float val; int idxr;
    preload(blockIdx.x, val, idxr);   // prologue load for first chunk

    for (int chunk = blockIdx.x; chunk < nchunks; chunk += gridDim.x) {
        const float val_cur = val;
        const int   idx_cur = idxr;
        // issue next chunk's gathers now; consumed one full iteration later
        preload(chunk + (int)gridDim.x, val, idxr);

        const int ebase = chunk * 128 + wave * 16;

        // ===== two temporal halves: layer0 -> 16-row LDS region -> A-frags =====
        bf16x8 afr[2][4];
#pragma unroll
        for (int half = 0; half < 2; ++half) {
#pragma unroll
            for (int le = 0; le < 8; le++) {
                int se = half * 8 + le;
                float vx = rdlane(val_cur, se * 4 + 0);
                float vy = rdlane(val_cur, se * 4 + 1);
                float vz = rdlane(val_cur, se * 4 + 2);
                float rr = rdlane(val_cur, se * 4 + 3);
                float cc0 = fmaf(w0q[0].x, rr, b0v[0]);
                float dd0 = fmaf(w0q[0].y, vx, fmaf(w0q[0].z, vy, w0q[0].w * vz));
                float cc1 = fmaf(w0q[1].x, rr, b0v[1]);
                float dd1 = fmaf(w0q[1].y, vx, fmaf(w0q[1].z, vy, w0q[1].w * vz));
                float s0, s1, s2, s3;
                silu2x4(cc0 + dd0, cc0 - dd0, cc1 + dd1, cc1 - dd1, s0, s1, s2, s3);
                bf16x2 pki, pkj;
                pki[0] = (__bf16)s0; pki[1] = (__bf16)s2;   // x_i: h=2l, 2l+1
                pkj[0] = (__bf16)s1; pkj[1] = (__bf16)s3;   // x_j
                int mi = 2 * le;                  // x_i row in [0,16); x_j row = mi+1
                int fr = wave * 4 + q;
                int sli = ((mi ^ q ^ (p << 2)) & 15) + (p << 4);
                int slj = (((mi + 1) ^ q ^ (p << 2)) & 15) + (p << 4);
                ((unsigned*)sH0)[fr * 256 + sli * 4 + bsub] = __builtin_bit_cast(unsigned, pki);
                ((unsigned*)sH0)[fr * 256 + slj * 4 + bsub] = __builtin_bit_cast(unsigned, pkj);
            }
            // cache this half's A-fragments before half 1 overwrites the region
#pragma unroll
            for (int ks = 0; ks < 4; ks++) {
                int sl_rd = (((lane & 15) ^ ks ^ (q << 2)) & 15) + 16 * q;
                afr[half][ks] = *(const bf16x8*)(&sH0[(wave * 4 + ks) * 512 + sl_rd * 8]);
            }
        }

        // ===== GEMM: h1_pre' = H0' @ W1^T + b1' (B read once, feeds both halves) =====
        f32x4 acc[2][8];
#pragma unroll
        for (int t = 0; t < 2; t++)
#pragma unroll
            for (int nt = 0; nt < 8; nt++)
                acc[t][nt] = (f32x4){b1v[nt], b1v[nt], b1v[nt], b1v[nt]};

#pragma unroll
        for (int ks = 0; ks < 4; ks++) {
#pragma unroll
            for (int nt = 0; nt < 8; nt++) {
                bf16x8 bb = *(const bf16x8*)(&sW1[(nt * 4 + ks) * 512 + lane * 8]);
                acc[0][nt] = __builtin_amdgcn_mfma_f32_16x16x32_bf16(afr[0][ks], bb, acc[0][nt], 0, 0, 0);
                acc[1][nt] = __builtin_amdgcn_mfma_f32_16x16x32_bf16(afr[1][ks], bb, acc[1][nt], 0, 0, 0);
            }
        }

        // ===== epilogue: silu2(h1') . (W2*ln2) -> +b2 -> packed f64 scatter-add =====
        float rs[2][4] = {{0.f, 0.f, 0.f, 0.f}, {0.f, 0.f, 0.f, 0.f}};
#pragma unroll
        for (int t = 0; t < 2; t++)
#pragma unroll
            for (int nt = 0; nt < 8; nt++) {
                float s0, s1, s2, s3;
                silu2x4(acc[t][nt][0], acc[t][nt][1], acc[t][nt][2], acc[t][nt][3],
                        s0, s1, s2, s3);
                rs[t][0] = fmaf(s0, w2v[nt], rs[t][0]);
                rs[t][1] = fmaf(s1, w2v[nt], rs[t][1]);
                rs[t][2] = fmaf(s2, w2v[nt], rs[t][2]);
                rs[t][3] = fmaf(s3, w2v[nt], rs[t][3]);
            }
#pragma unroll
        for (int t = 0; t < 2; t++)
#pragma unroll
            for (int r = 0; r < 4; r++) {
                float s = rs[t][r];
                s += __shfl_xor(s, 1, 64);
                s += __shfl_xor(s, 2, 64);
                s += __shfl_xor(s, 4, 64);
                s += __shfl_xor(s, 8, 64);
                int el  = t * 8 + q * 2 + (r >> 1);        // edge within wave's 16
                int src = el * 4 + (r & 1);                // comp0 lane holds i, comp1 holds j
                int node = __shfl(idx_cur, src, 64);
                int e = ebase + el;
                if (c == 0 && e < E) {
                    double contrib = (double)(s + b2f) + CNT_UNIT;
                    if (r & 1) atomicAdd(&acc_j[node], contrib);
                    else       atomicAdd(&acc_i[node], contrib);
                }
            }
        // wave-local LDS WAR across chunks is safe: one wave's DS ops are in-order.
    }
}

__global__ void finalize_kernel(const double* __restrict__ acc_i,
                                const double* __restrict__ acc_j,
                                float* __restrict__ out, int N)
{
    int n = blockIdx.x * 256 + threadIdx.x;
    if (n < N) {
        double ti = acc_i[n], tj = acc_j[n];
        double ci = rint(ti * (1.0 / CNT_UNIT));
        double cj = rint(tj * (1.0 / CNT_UNIT));
        double si = ti - ci * CNT_UNIT;
        double sj = tj - cj * CNT_UNIT;
        out[n] = (float)(si / fmax(ci, 1.0) + sj / fmax(cj, 1.0));
    }
}

extern "C" void kernel_launch(void* const* d_in, const int* in_sizes, int n_in,
                              void* d_out, int out_size, void* d_ws, size_t ws_size,
                              hipStream_t stream) {
    const float* v   = (const float*)d_in[0];
    const float* rij = (const float*)d_in[1];
    const float* W0  = (const float*)d_in[2];
    const float* b0  = (const float*)d_in[3];
    const float* W1  = (const float*)d_in[4];
    const float* b1  = (const float*)d_in[5];
    const float* W2  = (const float*)d_in[6];
    const float* b2  = (const float*)d_in[7];
    const int* eidx  = (const int*)d_in[8];

    const int E = in_sizes[1] / 3;
    const int N = out_size;

    double* acc_i = (double*)d_ws;
    double* acc_j = acc_i + N;

    hipMemsetAsync(d_ws, 0, (size_t)2 * N * sizeof(double), stream);

    int nchunks = (E + 127) / 128;      // 128 edges per block-chunk (8 waves)
    int grid = nchunks < 512 ? nchunks : 512;
    mlp_kernel<<<grid, 512, 0, stream>>>(v, rij, W0, b0, W1, b1, W2, b2, eidx,
                                         acc_i, acc_j, E, nchunks);
    finalize_kernel<<<(N + 255) / 256, 256, 0, stream>>>(acc_i, acc_j,
                                                         (float*)d_out, N);
}